// Round 3
// baseline (367.987 us; speedup 1.0000x reference)
//
#include <hip/hip_runtime.h>

#define NN 8192
#define EE 256
#define KNH 32
#define NKEEP 4096

typedef unsigned long long u64;
typedef unsigned int u32;

// ws layout:
// part    : [2][32][256] double @ 0        (131072 B)
// gm      : [2][256]     double @ 131072   (  4096 B)
// ld      : [2][8192]    double @ 135168   (131072 B)
// pos2idx : [2][4096]    int    @ 266240   ( 32768 B)

__global__ void k_gm_partial(const float* __restrict__ x, double* __restrict__ part) {
    const int b = blockIdx.y, chunk = blockIdx.x, t = threadIdx.x;
    const float* xp = x + ((size_t)b * NN + (size_t)chunk * 256) * EE + t;
    double s = 0.0;
    for (int i = 0; i < 256; ++i) s += (double)xp[(size_t)i * EE];
    part[((size_t)b * 32 + chunk) * EE + t] = s;
}

__global__ void k_gm_final(const double* __restrict__ part, double* __restrict__ gm) {
    const int b = blockIdx.y, t = threadIdx.x;
    double s = 0.0;
    for (int c = 0; c < 32; ++c) s += part[((size_t)b * 32 + c) * EE + t];
    gm[b * EE + t] = fabs(s / (double)NN);
}

__device__ __forceinline__ u64 wave_min_u64(u64 h) {
#pragma unroll
    for (int s = 1; s < 64; s <<= 1) {
        u32 hi = (u32)(h >> 32), lo = (u32)h;
        u32 ohi = __shfl_xor((int)hi, s);
        u32 olo = __shfl_xor((int)lo, s);
        u64 o = ((u64)ohi << 32) | olo;
        h = (o < h) ? o : h;
    }
    return h;
}

// One wave per point: top-32 NN via per-lane 8-deep register lists + wave merge,
// wave-uniform skip of the insert chain, exactness certificate + rare fallback.
__global__ void k_knn_dist(const float* __restrict__ x, const float* __restrict__ coords,
                           const double* __restrict__ gm, double* __restrict__ ld_ws,
                           float* __restrict__ ld_out) {
    const int b    = blockIdx.y;
    const int wid  = threadIdx.x >> 6;
    const int lane = threadIdx.x & 63;
    const int i    = blockIdx.x * 4 + wid;

    const float* cs0 = coords + (size_t)b * 2 * NN;
    const float* cs1 = cs0 + NN;
    const float ci0 = cs0[i];
    const float ci1 = cs1[i];

    // per-lane sorted (ascending) top-8 keys; key = (f32_dist_bits << 32) | j
    u64 K0 = ~0ull, K1 = ~0ull, K2 = ~0ull, K3 = ~0ull;
    u64 K4 = ~0ull, K5 = ~0ull, K6 = ~0ull, K7 = ~0ull;

#define INSERT(key)                                      \
    do {                                                 \
        const u64 _k = (key);                            \
        K7 = (_k < K6) ? K6 : ((_k < K7) ? _k : K7);     \
        K6 = (_k < K5) ? K5 : ((_k < K6) ? _k : K6);     \
        K5 = (_k < K4) ? K4 : ((_k < K5) ? _k : K5);     \
        K4 = (_k < K3) ? K3 : ((_k < K4) ? _k : K4);     \
        K3 = (_k < K2) ? K2 : ((_k < K3) ? _k : K3);     \
        K2 = (_k < K1) ? K1 : ((_k < K2) ? _k : K2);     \
        K1 = (_k < K0) ? K0 : ((_k < K1) ? _k : K1);     \
        K0 = (_k < K0) ? _k : K0;                        \
    } while (0)

    for (int t = 0; t < NN / 128; ++t) {
        const int j0 = lane + t * 128;
        const int j1 = j0 + 64;
        const float dx0 = ci0 - cs0[j0];
        const float dy0 = ci1 - cs1[j0];
        const float d0  = fmaf(dx0, dx0, dy0 * dy0);
        const float dx1 = ci0 - cs0[j1];
        const float dy1 = ci1 - cs1[j1];
        const float d1  = fmaf(dx1, dx1, dy1 * dy1);
        const u32 db0 = __float_as_uint(d0);
        const u32 db1 = __float_as_uint(d1);
        const u32 thr = (u32)(K7 >> 32);
        // wave-uniform skip: if no lane can improve its top-8, do nothing
        if (__any(db0 <= thr || db1 <= thr)) {
            INSERT(((u64)db0 << 32) | (u32)j0);
            INSERT(((u64)db1 << 32) | (u32)j1);
        }
    }
    const u64 Kworst = K7;   // all dropped candidates have key >= Kworst

    // merge 64 sorted 8-lists: 32 rounds of wave-argmin with pop
    int jkeep = 0;           // lane k ends holding the k-th nearest index (k<32)
    u64 key32 = 0;           // key of the last (32nd) selected
    for (int k = 0; k < KNH; ++k) {
        const u64 h = wave_min_u64(K0);
        if (lane == k) jkeep = (int)(u32)h;
        key32 = h;
        const bool pop = (K0 == h);   // keys unique -> exactly one lane pops
        K0 = pop ? K1 : K0;
        K1 = pop ? K2 : K1;
        K2 = pop ? K3 : K2;
        K3 = pop ? K4 : K3;
        K4 = pop ? K5 : K4;
        K5 = pop ? K6 : K5;
        K6 = pop ? K7 : K6;
        K7 = pop ? ~0ull : K7;
    }

    // exactness certificate: no lane may have dropped a candidate below key32
    if (!__all(Kworst >= key32)) {
        // exact fallback: 32 rounds, each re-streams all candidates
        u64 minkeep = 0;
        for (int k = 0; k < KNH; ++k) {
            u64 best = ~0ull;
            for (int t = 0; t < NN / 64; ++t) {
                const int j = lane + t * 64;
                const float dx = ci0 - cs0[j];
                const float dy = ci1 - cs1[j];
                const float d  = fmaf(dx, dx, dy * dy);
                const u64 key = ((u64)__float_as_uint(d) << 32) | (u32)j;
                if (key >= minkeep && key < best) best = key;
            }
            const u64 h = wave_min_u64(best);
            if (lane == k) jkeep = (int)(u32)h;
            minkeep = h + 1;
        }
    }

    // gather 32 neighbor rows, accumulate sum & sumsq per channel (4 ch/lane)
    double s1[4] = {0.0, 0.0, 0.0, 0.0};
    double s2[4] = {0.0, 0.0, 0.0, 0.0};
    const float* xb = x + (size_t)b * NN * EE;
    for (int k = 0; k < KNH; ++k) {
        const int j = __shfl(jkeep, k);
        const float4 v = *reinterpret_cast<const float4*>(xb + (size_t)j * EE + (lane << 2));
        const double v0 = (double)v.x, v1 = (double)v.y, v2 = (double)v.z, v3 = (double)v.w;
        s1[0] += v0; s2[0] += v0 * v0;
        s1[1] += v1; s2[1] += v1 * v1;
        s1[2] += v2; s2[2] += v2 * v2;
        s1[3] += v3; s2[3] += v3 * v3;
    }

    const double* gmb = gm + b * EE;
    double t = 0.0;
#pragma unroll
    for (int q = 0; q < 4; ++q) {
        const double sum = s1[q];
        double ssd = s2[q] - sum * sum * (1.0 / 32.0);
        ssd = ssd > 0.0 ? ssd : 0.0;
        const double ls = sqrt(ssd / 31.0);
        t += ls / gmb[(lane << 2) + q];
    }
#pragma unroll
    for (int s = 1; s < 64; s <<= 1) t += __shfl_xor(t, s);

    if (lane == 0) {
        ld_ws [(size_t)b * NN + i] = t;
        ld_out[(size_t)b * NN + i] = (float)t;
    }
}

// exact rank (= output position in desc top_k order with index tie-break)
// one wave per point
__global__ void k_rank(const double* __restrict__ ld, int* __restrict__ pos2idx) {
    const int b    = blockIdx.y;
    const int wid  = threadIdx.x >> 6;
    const int lane = threadIdx.x & 63;
    const int i    = blockIdx.x * 4 + wid;
    const double* lb = ld + (size_t)b * NN;
    const double di = lb[i];
    int cnt = 0;
    for (int t = 0; t < NN / 64; ++t) {
        const int j = lane + t * 64;
        const double dj = lb[j];
        cnt += (dj > di || (dj == di && j < i)) ? 1 : 0;
    }
#pragma unroll
    for (int s = 1; s < 64; s <<= 1) cnt += __shfl_xor(cnt, s);
    if (lane == 0 && cnt < NKEEP) pos2idx[b * NKEEP + cnt] = i;
}

__global__ void k_gather(const float* __restrict__ x, const float* __restrict__ coords,
                         const int* __restrict__ pos2idx,
                         float* __restrict__ x_out, float* __restrict__ c_out) {
    const int b    = blockIdx.y;
    const int wid  = threadIdx.x >> 6;
    const int lane = threadIdx.x & 63;
    const int r    = blockIdx.x * 4 + wid;
    const int i    = pos2idx[b * NKEEP + r];
    const float4 v = *reinterpret_cast<const float4*>(x + ((size_t)b * NN + i) * EE + (lane << 2));
    *reinterpret_cast<float4*>(x_out + ((size_t)b * NKEEP + r) * EE + (lane << 2)) = v;
    if (lane < 2) {
        c_out[((size_t)b * 2 + lane) * NKEEP + r] = coords[((size_t)b * 2 + lane) * NN + i];
    }
}

extern "C" void kernel_launch(void* const* d_in, const int* in_sizes, int n_in,
                              void* d_out, int out_size, void* d_ws, size_t ws_size,
                              hipStream_t stream) {
    const float* x      = (const float*)d_in[0];
    const float* coords = (const float*)d_in[1];

    float* out    = (float*)d_out;
    float* x_out  = out;                 // [2][4096][256]
    float* c_out  = out + 2097152;       // [2][2][4096][1]
    float* ld_out = out + 2113536;       // [2][8192]

    char*   ws      = (char*)d_ws;
    double* part    = (double*)(ws);
    double* gm      = (double*)(ws + 131072);
    double* ld      = (double*)(ws + 135168);
    int*    pos2idx = (int*)  (ws + 266240);

    k_gm_partial<<<dim3(32, 2),   256, 0, stream>>>(x, part);
    k_gm_final  <<<dim3(1, 2),    256, 0, stream>>>(part, gm);
    k_knn_dist  <<<dim3(2048, 2), 256, 0, stream>>>(x, coords, gm, ld, ld_out);
    k_rank      <<<dim3(2048, 2), 256, 0, stream>>>(ld, pos2idx);
    k_gather    <<<dim3(1024, 2), 256, 0, stream>>>(x, coords, pos2idx, x_out, c_out);
}

// Round 4
// 158.678 us; speedup vs baseline: 2.3191x; 2.3191x over previous
//
#include <hip/hip_runtime.h>

#define NN 8192
#define EE 256
#define KNH 32
#define NKEEP 4096

typedef unsigned long long u64;
typedef unsigned int u32;

// ws layout (f32):
// gmpart : [2][32][256] f32 @ 0      (65536 B)
// gm     : [2][256]     f32 @ 65536  ( 2048 B)
// ld     : [2][8192]    f32 @ 67584  (65536 B)

__global__ void k_gm_partial(const float* __restrict__ x, float* __restrict__ part) {
    const int b = blockIdx.y, chunk = blockIdx.x, t = threadIdx.x;
    const float* xp = x + ((size_t)b * NN + (size_t)chunk * 256) * EE + t;
    float s = 0.0f;
    for (int i = 0; i < 256; ++i) s += xp[(size_t)i * EE];
    part[((size_t)b * 32 + chunk) * EE + t] = s;
}

__global__ void k_gm_final(const float* __restrict__ part, float* __restrict__ gm) {
    const int b = blockIdx.y, t = threadIdx.x;
    float s = 0.0f;
    for (int c = 0; c < 32; ++c) s += part[((size_t)b * 32 + c) * EE + t];
    gm[b * EE + t] = fabsf(s / (float)NN);
}

__device__ __forceinline__ u64 shfl_xor_u64(u64 v, int m) {
    u32 hi = (u32)(v >> 32), lo = (u32)v;
    hi = (u32)__shfl_xor((int)hi, m);
    lo = (u32)__shfl_xor((int)lo, m);
    return ((u64)hi << 32) | lo;
}

__device__ __forceinline__ u64 wave_min_u64(u64 h) {
#pragma unroll
    for (int s = 1; s < 64; s <<= 1) {
        const u64 o = shfl_xor_u64(h, s);
        h = (o < h) ? o : h;
    }
    return h;
}

// One wave per point. Pass1: per-lane top-4 f32 distances. T = 32nd smallest of
// kept (ballot binary search) >= true d32. Pass2: collect all d<=T into LDS,
// bitonic-sort (d,j) keys -> exact top-32. Certificate M>64 -> exact fallback.
__global__ void k_knn_dist(const float* __restrict__ x, const float* __restrict__ coords,
                           const float* __restrict__ gm, float* __restrict__ ld_ws,
                           float* __restrict__ ld_out) {
    __shared__ u64 coll[4][64];
    const int b    = blockIdx.y;
    const int wid  = threadIdx.x >> 6;
    const int lane = threadIdx.x & 63;
    const int i    = blockIdx.x * 4 + wid;

    const float* cs0 = coords + (size_t)b * 2 * NN;
    const float* cs1 = cs0 + NN;
    const float ci0 = cs0[i];
    const float ci1 = cs1[i];

    // ---- pass 1: per-lane top-4 distances (f32, ascending) ----
    float K0 = 1e30f, K1 = 1e30f, K2 = 1e30f, K3 = 1e30f;
#define INS4(d)                                          \
    do {                                                 \
        const float _d = (d);                            \
        K3 = (_d < K2) ? K2 : ((_d < K3) ? _d : K3);     \
        K2 = (_d < K1) ? K1 : ((_d < K2) ? _d : K2);     \
        K1 = (_d < K0) ? K0 : ((_d < K1) ? _d : K1);     \
        K0 = fminf(_d, K0);                              \
    } while (0)

    for (int t = 0; t < NN / 128; ++t) {
        const int j0 = lane + t * 128;
        const int j1 = j0 + 64;
        const float dx0 = ci0 - cs0[j0];
        const float dy0 = ci1 - cs1[j0];
        const float d0  = fmaf(dx0, dx0, dy0 * dy0);
        const float dx1 = ci0 - cs0[j1];
        const float dy1 = ci1 - cs1[j1];
        const float d1  = fmaf(dx1, dx1, dy1 * dy1);
        INS4(d0);
        INS4(d1);
    }

    // ---- threshold: minimal T with count(kept_bits <= T) >= 32 ----
    const u32 k0 = __float_as_uint(K0), k1 = __float_as_uint(K1);
    const u32 k2 = __float_as_uint(K2), k3 = __float_as_uint(K3);
    u32 lo = 0, hi = 0xFFFFFFFFu;
    for (int it = 0; it < 32; ++it) {
        const u32 mid = lo + ((hi - lo) >> 1);
        const int c = __popcll(__ballot(k0 <= mid)) + __popcll(__ballot(k1 <= mid))
                    + __popcll(__ballot(k2 <= mid)) + __popcll(__ballot(k3 <= mid));
        if (c >= KNH) hi = mid; else lo = mid + 1;
    }
    const u32 T = hi;

    // ---- pass 2: collect all candidates with d_bits <= T ----
    const u64 lmask = (1ull << lane) - 1;
    int base = 0;
    for (int t = 0; t < NN / 128; ++t) {
        const int j0 = lane + t * 128;
        const int j1 = j0 + 64;
        const float dx0 = ci0 - cs0[j0];
        const float dy0 = ci1 - cs1[j0];
        const float d0  = fmaf(dx0, dx0, dy0 * dy0);
        const float dx1 = ci0 - cs0[j1];
        const float dy1 = ci1 - cs1[j1];
        const float d1  = fmaf(dx1, dx1, dy1 * dy1);
        const u32 b0 = __float_as_uint(d0);
        const u32 b1 = __float_as_uint(d1);
        const bool p0 = (b0 <= T);
        const bool p1 = (b1 <= T);
        if (__any(p0 | p1)) {
            const u64 m0 = __ballot(p0);
            const int pos0 = base + __popcll(m0 & lmask);
            base += __popcll(m0);
            const u64 m1 = __ballot(p1);
            const int pos1 = base + __popcll(m1 & lmask);
            base += __popcll(m1);
            if (p0 && pos0 < 64) coll[wid][pos0] = ((u64)b0 << 32) | (u32)j0;
            if (p1 && pos1 < 64) coll[wid][pos1] = ((u64)b1 << 32) | (u32)j1;
        }
    }
    const bool ovf = (base > 64);
    __syncthreads();

    // ---- bitonic sort (ascending) of up to 64 keys across lanes ----
    u64 key = (lane < base) ? coll[wid][lane] : ~0ull;
#pragma unroll
    for (int k = 2; k <= 64; k <<= 1) {
#pragma unroll
        for (int j = k >> 1; j > 0; j >>= 1) {
            const u64 other = shfl_xor_u64(key, j);
            const bool keep_min = (((lane & j) == 0) == ((lane & k) == 0));
            const bool lt = (key < other);
            const u64 mn = lt ? key : other;
            const u64 mx = lt ? other : key;
            key = keep_min ? mn : mx;
        }
    }
    int jkeep = (int)(u32)key;   // lane m holds m-th nearest (m < 32)

    // ---- certificate fallback (exact restream), ~never taken ----
    if (ovf) {
        u64 minkeep = 0;
        for (int k = 0; k < KNH; ++k) {
            u64 best = ~0ull;
            for (int t = 0; t < NN / 64; ++t) {
                const int j = lane + t * 64;
                const float dx = ci0 - cs0[j];
                const float dy = ci1 - cs1[j];
                const float d  = fmaf(dx, dx, dy * dy);
                const u64 kk = ((u64)__float_as_uint(d) << 32) | (u32)j;
                if (kk >= minkeep && kk < best) best = kk;
            }
            const u64 h = wave_min_u64(best);
            if (lane == k) jkeep = (int)(u32)h;
            minkeep = h + 1;
        }
    }

    // ---- gather 32 rows, f32 sum/sumsq (4 channels per lane) ----
    float s1[4] = {0.f, 0.f, 0.f, 0.f};
    float s2[4] = {0.f, 0.f, 0.f, 0.f};
    const float* xb = x + (size_t)b * NN * EE;
#pragma unroll 8
    for (int k = 0; k < KNH; ++k) {
        const int j = __shfl(jkeep, k);
        const float4 v = *reinterpret_cast<const float4*>(xb + (size_t)j * EE + (lane << 2));
        s1[0] += v.x; s2[0] += v.x * v.x;
        s1[1] += v.y; s2[1] += v.y * v.y;
        s1[2] += v.z; s2[2] += v.z * v.z;
        s1[3] += v.w; s2[3] += v.w * v.w;
    }

    const float* gmb = gm + b * EE;
    float tt = 0.f;
#pragma unroll
    for (int q = 0; q < 4; ++q) {
        const float sum = s1[q];
        float ssd = s2[q] - sum * sum * (1.0f / 32.0f);
        ssd = ssd > 0.f ? ssd : 0.f;
        const float ls = sqrtf(ssd * (1.0f / 31.0f));
        tt += ls / gmb[(lane << 2) + q];
    }
#pragma unroll
    for (int s = 1; s < 64; s <<= 1) tt += __shfl_xor(tt, s);

    if (lane == 0) {
        ld_ws [(size_t)b * NN + i] = tt;
        ld_out[(size_t)b * NN + i] = tt;
    }
}

// one wave per point: exact rank (desc, index tie-break) + direct row gather
__global__ void k_rank_gather(const float* __restrict__ x, const float* __restrict__ coords,
                              const float* __restrict__ ld,
                              float* __restrict__ x_out, float* __restrict__ c_out) {
    const int b    = blockIdx.y;
    const int wid  = threadIdx.x >> 6;
    const int lane = threadIdx.x & 63;
    const int i    = blockIdx.x * 4 + wid;
    const float* lb = ld + (size_t)b * NN;
    const float di = lb[i];
    int cnt = 0;
    for (int t = 0; t < NN / 64; ++t) {
        const int j = lane + t * 64;
        const float dj = lb[j];
        cnt += (dj > di || (dj == di && j < i)) ? 1 : 0;
    }
#pragma unroll
    for (int s = 1; s < 64; s <<= 1) cnt += __shfl_xor(cnt, s);

    if (cnt < NKEEP) {
        const float4 v = *reinterpret_cast<const float4*>(x + ((size_t)b * NN + i) * EE + (lane << 2));
        *reinterpret_cast<float4*>(x_out + ((size_t)b * NKEEP + cnt) * EE + (lane << 2)) = v;
        if (lane < 2) {
            c_out[((size_t)b * 2 + lane) * NKEEP + cnt] = coords[((size_t)b * 2 + lane) * NN + i];
        }
    }
}

extern "C" void kernel_launch(void* const* d_in, const int* in_sizes, int n_in,
                              void* d_out, int out_size, void* d_ws, size_t ws_size,
                              hipStream_t stream) {
    const float* x      = (const float*)d_in[0];
    const float* coords = (const float*)d_in[1];

    float* out    = (float*)d_out;
    float* x_out  = out;                 // [2][4096][256]
    float* c_out  = out + 2097152;       // [2][2][4096][1]
    float* ld_out = out + 2113536;       // [2][8192]

    char*  ws   = (char*)d_ws;
    float* part = (float*)(ws);
    float* gm   = (float*)(ws + 65536);
    float* ld   = (float*)(ws + 67584);

    k_gm_partial <<<dim3(32, 2),   256, 0, stream>>>(x, part);
    k_gm_final   <<<dim3(1, 2),    256, 0, stream>>>(part, gm);
    k_knn_dist   <<<dim3(2048, 2), 256, 0, stream>>>(x, coords, gm, ld, ld_out);
    k_rank_gather<<<dim3(2048, 2), 256, 0, stream>>>(x, coords, ld, x_out, c_out);
}